// Round 15
// baseline (742.821 us; speedup 1.0000x reference)
//
#include <hip/hip_runtime.h>
#include <math.h>

#define B_ROWS 8192
#define P_KEYS 2048
#define D_DIM  768
#define L_LEN  5
#define K_SEL  5
#define EPSV   1e-8f

#define CBLK   64                  // cols per approx block
#define NCB2   (P_KEYS / CBLK)     // 32 col blocks
#define RBLK   128                 // rows per approx block
#define KC     32                  // k chunk (MFMA K)
#define NKC    (D_DIM / KC)        // 24
#define NCAND  (NCB2 * K_SEL)      // 160 candidates per row
#define NRESC  16                  // exact-rescored candidates per row

typedef _Float16 half8  __attribute__((ext_vector_type(8)));
typedef _Float16 half4v __attribute__((ext_vector_type(4)));
typedef float    f32x4  __attribute__((ext_vector_type(4)));

// sorted ascending (v[0] best). Tie-break: lower index wins (jax top_k semantics).
__device__ inline void insert5(float (&v)[K_SEL], int (&ix)[K_SEL], float nv, int ni) {
    if (nv < v[K_SEL-1] || (nv == v[K_SEL-1] && ni < ix[K_SEL-1])) {
        v[K_SEL-1] = nv; ix[K_SEL-1] = ni;
        #pragma unroll
        for (int j = K_SEL-1; j > 0; --j) {
            bool sw = (v[j] < v[j-1]) || (v[j] == v[j-1] && ix[j] < ix[j-1]);
            if (sw) {
                float tv = v[j]; v[j] = v[j-1]; v[j-1] = tv;
                int   ti = ix[j]; ix[j] = ix[j-1]; ix[j-1] = ti;
            }
        }
    }
}

// One wave per row. waves [0, P_KEYS): normalize pool_key -> kn (fp32, for the
// exact rescore — numerics must match the r14-passing pre-normalized form) and
// kh (fp16, for the MFMA approx pass). waves [P_KEYS, ...): x -> inv_x.
__global__ __launch_bounds__(256)
void norm_kernel(const float* __restrict__ x, const float* __restrict__ pk,
                 float* __restrict__ kn, _Float16* __restrict__ kh,
                 float* __restrict__ inv_x) {
    int wave = (blockIdx.x * blockDim.x + threadIdx.x) >> 6;
    int lane = threadIdx.x & 63;
    bool is_key = (wave < P_KEYS);
    int row = is_key ? wave : wave - P_KEYS;
    const float* src = is_key ? (pk + (size_t)row * D_DIM) : (x + (size_t)row * D_DIM);

    const float4* s4 = (const float4*)src;
    float4 v[3];
    float s = 0.f;
    #pragma unroll
    for (int i = 0; i < 3; ++i) {
        v[i] = s4[lane + 64 * i];
        s += v[i].x * v[i].x + v[i].y * v[i].y + v[i].z * v[i].z + v[i].w * v[i].w;
    }
    #pragma unroll
    for (int off = 32; off; off >>= 1) s += __shfl_xor(s, off, 64);
    float inv = 1.0f / fmaxf(sqrtf(s), EPSV);

    if (is_key) {
        float4* d4 = (float4*)(kn + (size_t)row * D_DIM);
        #pragma unroll
        for (int i = 0; i < 3; ++i) {
            float4 w = v[i];
            w.x *= inv; w.y *= inv; w.z *= inv; w.w *= inv;
            d4[lane + 64 * i] = w;
            half4v h = { (_Float16)w.x, (_Float16)w.y, (_Float16)w.z, (_Float16)w.w };
            *(half4v*)(kh + (size_t)row * D_DIM + (lane + 64 * i) * 4) = h;
        }
    } else {
        if (lane == 0) inv_x[row] = inv;
    }
}

// Approx pass: fp16 MFMA (fp32 accum) of x_hat . k_hat, per-row top-5 per
// 64-col block. grid = (NCB2=32, B_ROWS/RBLK=64), block 512 (8 waves x 16 rows).
// Fragment layouts (gfx950 16x16x32, m89-verified C/D): A lane l holds
// A[m=l&15][k=(l>>4)*8+j]; B lane l holds B[k=(l>>4)*8+j][n=l&15];
// D lane l holds D[m=(l>>4)*4+reg][n=l&15].
// LDS rows padded to 5 slots of 16B (80B stride) -> <=2-way bank aliasing.
// fp16 margin: dot error ~6e-4 << rank-5..16 distance gap ~0.012, so the true
// fp32 top-5 is contained in these candidates; exact fp32 rescore decides.
__global__ __launch_bounds__(512)
void approx_kernel(const float* __restrict__ x, const _Float16* __restrict__ kh,
                   const float* __restrict__ inv_x,
                   float* __restrict__ cand_val, unsigned short* __restrict__ cand_idx) {
    const int cb = blockIdx.x, rb = blockIdx.y;
    const int col0 = cb * CBLK, row0 = rb * RBLK;
    const int tid = threadIdx.x, lane = tid & 63, w = tid >> 6;

    __shared__ _Float16 ash[RBLK][5][8];   // [row][kg slot(4 used + pad)][8]
    __shared__ _Float16 khs[CBLK][5][8];   // [col][kg slot][8]

    // staging: A = 128 rows x 4 kgroups (all 512 threads), B = 64 cols x 4 kg (tid<256)
    const int arow = tid >> 2, akg = tid & 3;
    const float invxs = inv_x[row0 + arow];
    const float* apt = x + (size_t)(row0 + arow) * D_DIM + akg * 8;
    const int bcol = (tid >> 2) & 63, bkg = tid & 3;
    const _Float16* bpt = kh + (size_t)(col0 + bcol) * D_DIM + bkg * 8;

    f32x4 acc[4];
    #pragma unroll
    for (int t = 0; t < 4; ++t) acc[t] = (f32x4){0.f, 0.f, 0.f, 0.f};

    const int fr = w * 16 + (lane & 15);   // A-frag row in ash
    const int fk = lane >> 4;              // frag k-group

    for (int kc = 0; kc < NKC; ++kc) {
        const int k0 = kc * KC;
        float4 xa = *(const float4*)(apt + k0);
        float4 xb = *(const float4*)(apt + k0 + 4);
        uint4 bv = {0, 0, 0, 0};
        if (tid < 256) bv = *(const uint4*)(bpt + k0);
        __syncthreads();                   // prior chunk's ds_reads done
        half8 hv;
        hv[0] = (_Float16)(xa.x * invxs); hv[1] = (_Float16)(xa.y * invxs);
        hv[2] = (_Float16)(xa.z * invxs); hv[3] = (_Float16)(xa.w * invxs);
        hv[4] = (_Float16)(xb.x * invxs); hv[5] = (_Float16)(xb.y * invxs);
        hv[6] = (_Float16)(xb.z * invxs); hv[7] = (_Float16)(xb.w * invxs);
        *(half8*)&ash[arow][akg][0] = hv;
        if (tid < 256) *(uint4*)&khs[bcol][bkg][0] = bv;
        __syncthreads();

        half8 a = *(const half8*)&ash[fr][fk][0];
        #pragma unroll
        for (int t = 0; t < 4; ++t) {
            half8 b = *(const half8*)&khs[t * 16 + (lane & 15)][fk][0];
            acc[t] = __builtin_amdgcn_mfma_f32_16x16x32_f16(a, b, acc[t], 0, 0, 0);
        }
    }

    // epilogue: lane holds rows (lane>>4)*4+r of its wave strip, col t*16+(lane&15)
    #pragma unroll
    for (int r = 0; r < 4; ++r) {
        float tv[K_SEL]; int tix[K_SEL];
        #pragma unroll
        for (int j = 0; j < K_SEL; ++j) { tv[j] = 3.0e38f; tix[j] = 0x7fffffff; }
        #pragma unroll
        for (int t = 0; t < 4; ++t)
            insert5(tv, tix, 1.0f - acc[t][r], col0 + t * 16 + (lane & 15));
        #pragma unroll
        for (int off = 1; off < 16; off <<= 1) {
            float ov[K_SEL]; int oi[K_SEL];
            #pragma unroll
            for (int j = 0; j < K_SEL; ++j) {
                ov[j] = __shfl_xor(tv[j], off, 16);
                oi[j] = __shfl_xor(tix[j], off, 16);
            }
            #pragma unroll
            for (int j = 0; j < K_SEL; ++j) insert5(tv, tix, ov[j], oi[j]);
        }
        if ((lane & 15) == 0) {
            int grow = row0 + w * 16 + (lane >> 4) * 4 + r;
            #pragma unroll
            for (int j = 0; j < K_SEL; ++j) {
                cand_val[(size_t)grow * NCAND + cb * K_SEL + j] = tv[j];
                cand_idx[(size_t)grow * NCAND + cb * K_SEL + j] = (unsigned short)tix[j];
            }
        }
    }
}

// Per row: rank the 160 approx candidates, exactly rescore the approx-top-16
// (fp32, sequential ascending-k, (x[k]*inv_x) rounded then FMA — bitwise the
// r14-passing numerics), final top-5 by (exact value, index).
__global__ __launch_bounds__(256)
void select_rescore_kernel(const float* __restrict__ x, const float* __restrict__ kn,
                           const float* __restrict__ inv_x,
                           const float* __restrict__ cand_val,
                           const unsigned short* __restrict__ cand_idx,
                           float* __restrict__ out_dist, int* __restrict__ final_idx) {
    const int row = blockIdx.x, tid = threadIdx.x;
    __shared__ float avals[256];
    __shared__ int   aidx[256];
    __shared__ int   sel[NRESC];
    __shared__ float dsel[NRESC];

    float v = 3.0e38f; int ix = 0x7fffffff;
    if (tid < NCAND) {
        v  = cand_val[(size_t)row * NCAND + tid];
        ix = cand_idx[(size_t)row * NCAND + tid];
    }
    avals[tid] = v; aidx[tid] = ix;
    __syncthreads();
    int rank = 0;
    for (int i = 0; i < 256; ++i) {
        float ov = avals[i]; int oi = aidx[i];
        rank += (ov < v) || (ov == v && oi < ix);
    }
    if (tid < NCAND && rank < NRESC) sel[rank] = ix;   // total order -> bijective
    __syncthreads();
    if (tid < NRESC) {
        int c = sel[tid];
        float invx = inv_x[row];
        const float4* xp = (const float4*)(x + (size_t)row * D_DIM);
        const float4* bp = (const float4*)(kn + (size_t)c * D_DIM);
        float s = 0.f;
        for (int k = 0; k < D_DIM / 4; ++k) {
            float4 xv = xp[k], bv = bp[k];
            s += (xv.x * invx) * bv.x;
            s += (xv.y * invx) * bv.y;
            s += (xv.z * invx) * bv.z;
            s += (xv.w * invx) * bv.w;
        }
        dsel[tid] = 1.0f - s;
    }
    __syncthreads();
    if (tid == 0) {
        float fv[K_SEL]; int fi[K_SEL];
        #pragma unroll
        for (int j = 0; j < K_SEL; ++j) { fv[j] = 3.0e38f; fi[j] = 0x7fffffff; }
        for (int i = 0; i < NRESC; ++i) insert5(fv, fi, dsel[i], sel[i]);
        #pragma unroll
        for (int j = 0; j < K_SEL; ++j) {
            out_dist[(size_t)row * K_SEL + j] = fv[j];
            final_idx[(size_t)row * K_SEL + j] = fi[j];
        }
    }
}

// one block per (b, s): copy prompts[idx] (5*768 floats = 960 float4) to output
__global__ __launch_bounds__(256)
void gather_kernel(const float* __restrict__ prompts, const int* __restrict__ final_idx,
                   float* __restrict__ out1) {
    int bs = blockIdx.x;                 // 0 .. B_ROWS*K_SEL-1
    int p = final_idx[bs];
    const float4* src = (const float4*)(prompts + (size_t)p * (L_LEN * D_DIM));
    float4* dst = (float4*)(out1 + (size_t)bs * (L_LEN * D_DIM));
    const int n4 = (L_LEN * D_DIM) / 4;  // 960
    for (int i = threadIdx.x; i < n4; i += blockDim.x) dst[i] = src[i];
}

extern "C" void kernel_launch(void* const* d_in, const int* in_sizes, int n_in,
                              void* d_out, int out_size, void* d_ws, size_t ws_size,
                              hipStream_t stream) {
    const float* x       = (const float*)d_in[0];   // [8192, 768]
    const float* pk      = (const float*)d_in[1];   // [2048, 768]
    const float* prompts = (const float*)d_in[2];   // [2048, 5, 768]

    float* out_dist = (float*)d_out;                          // [8192, 5]
    float* out_pr   = (float*)d_out + (size_t)B_ROWS * K_SEL; // [8192, 5, 5, 768]

    char* ws = (char*)d_ws;
    float*          kn       = (float*)(ws);                      //  6,291,456 B
    _Float16*       kh       = (_Float16*)(ws + 6291456);         //  3,145,728 B
    float*          inv_x    = (float*)(ws + 9437184);            //     32,768 B
    float*          cand_val = (float*)(ws + 9469952);            //  5,242,880 B
    unsigned short* cand_idx = (unsigned short*)(ws + 14712832);  //  2,621,440 B
    int*            final_ix = (int*)(ws + 17334272);             //    163,840 B

    // 1) normalize keys -> kn (fp32) + kh (fp16); x -> inv_x
    norm_kernel<<<(P_KEYS + B_ROWS) / 4, 256, 0, stream>>>(x, pk, kn, kh, inv_x);
    // 2) fp16 MFMA approx distances + per-row/per-64col top-5 candidates
    {
        dim3 grid(NCB2, B_ROWS / RBLK);   // (32, 64); cb-major => x row-slab L2 reuse
        approx_kernel<<<grid, 512, 0, stream>>>(x, kh, inv_x, cand_val, cand_idx);
    }
    // 3) per-row candidate ranking + exact fp32 rescore of top-16 + final top-5
    select_rescore_kernel<<<B_ROWS, 256, 0, stream>>>(x, kn, inv_x, cand_val, cand_idx,
                                                      out_dist, final_ix);
    // 4) gather prompts
    gather_kernel<<<B_ROWS * K_SEL, 256, 0, stream>>>(prompts, final_ix, out_pr);
}